// Round 1
// 885.340 us; speedup vs baseline: 2.1721x; 2.1721x over previous
//
#include <hip/hip_runtime.h>
#include <hip/hip_bf16.h>
#include <math.h>

// Problem constants
#define BATCH 16
#define DIM 256
#define HEADS 8
#define HD 32
#define GRID_ 64
#define NTOK 4096            // GRID_*GRID_
#define WS 8
#define NQ 8
#define POOL 4
#define HP 16                // GRID_/POOL
#define NPOOL 256            // HP*HP
#define NW 8                 // GRID_/WS
#define NWTOK 64             // WS*WS
#define KVLEN 72             // NWTOK + NQ
#define SCALE 0.17677669529663687f   // HD^-0.5

typedef short short8 __attribute__((ext_vector_type(8)));
typedef float f32x4 __attribute__((ext_vector_type(4)));

typedef __hip_bfloat16 bf16;

__device__ inline short f2bf_bits(float f) {
    bf16 h = __float2bfloat16(f);
    return *reinterpret_cast<short*>(&h);
}

// ---------------- float -> bf16 conversion (weights) ------------------------
__global__ void f2bf_kernel(const float* __restrict__ src, bf16* __restrict__ dst, int n) {
    int i = blockIdx.x * 256 + threadIdx.x;
    if (i < n) dst[i] = __float2bfloat16(src[i]);
}

// ---------------- LayerNorm: one block (256 threads) per row ----------------
__device__ inline void store_val(float* p, float v) { *p = v; }
__device__ inline void store_val(bf16* p, float v) { *p = __float2bfloat16(v); }

template <typename OT>
__global__ void ln_kernel(const float* __restrict__ x, const float* __restrict__ g,
                          const float* __restrict__ bb, OT* __restrict__ y) {
    int row = blockIdx.x;
    int t = threadIdx.x;
    float v = x[(size_t)row * 256 + t];
    float s = v, sq = v * v;
    #pragma unroll
    for (int o = 32; o > 0; o >>= 1) {
        s += __shfl_down(s, o);
        sq += __shfl_down(sq, o);
    }
    __shared__ float ls[4], lq[4];
    __shared__ float mean_s, rstd_s;
    int w = t >> 6;
    if ((t & 63) == 0) { ls[w] = s; lq[w] = sq; }
    __syncthreads();
    if (t == 0) {
        float S = ls[0] + ls[1] + ls[2] + ls[3];
        float Q = lq[0] + lq[1] + lq[2] + lq[3];
        float m = S * (1.0f / 256.0f);
        float var = Q * (1.0f / 256.0f) - m * m;
        mean_s = m;
        rstd_s = rsqrtf(var + 1e-5f);
    }
    __syncthreads();
    store_val(&y[(size_t)row * 256 + t], (v - mean_s) * rstd_s * g[t] + bb[t]);
}

// ---------------- 4x4 avg pool: xn (B,4096,256) bf16 -> pooled f32 ----------
__global__ void pool_kernel(const bf16* __restrict__ xn, float* __restrict__ pooled) {
    int bp = blockIdx.x;          // b*256 + p
    int b = bp >> 8, p = bp & 255;
    int ph = p >> 4, pw = p & 15;
    int c = threadIdx.x;
    float s = 0.f;
    #pragma unroll
    for (int i = 0; i < 4; i++)
        #pragma unroll
        for (int j = 0; j < 4; j++) {
            int n = (ph * 4 + i) * GRID_ + pw * 4 + j;
            s += __bfloat162float(xn[((size_t)b * NTOK + n) * 256 + c]);
        }
    pooled[(size_t)bp * 256 + c] = s * 0.0625f;
}

// ---------------- small fp32 tiled GEMM (kproj/vproj/gk/gv) -----------------
#define MM_PLAIN 0
#define MM_BN 1      // e0=mean e1=var e2=gamma e3=beta
template <int MODE>
__global__ void mm_kernel(const float* __restrict__ A, const float* __restrict__ W,
                          const float* __restrict__ bias, float* __restrict__ out,
                          int K, int N,
                          const float* __restrict__ e0, const float* __restrict__ e1,
                          const float* __restrict__ e2, const float* __restrict__ e3) {
    __shared__ float As[64][17];
    __shared__ float Bs[64][17];
    int t = threadIdx.x;
    int ty = t >> 4, tx = t & 15;
    size_t rowBase = (size_t)blockIdx.y * 64;
    int colBase = blockIdx.x * 64;
    float acc[4][4] = {};
    for (int k0 = 0; k0 < K; k0 += 16) {
        #pragma unroll
        for (int l = 0; l < 4; l++) {
            int e = t + l * 256;
            int r = e >> 4, kk = e & 15;
            As[r][kk] = A[(rowBase + r) * (size_t)K + k0 + kk];
            Bs[r][kk] = W[((size_t)colBase + r) * K + k0 + kk];
        }
        __syncthreads();
        #pragma unroll
        for (int kk = 0; kk < 16; kk++) {
            float a[4], b[4];
            #pragma unroll
            for (int i = 0; i < 4; i++) a[i] = As[ty * 4 + i][kk];
            #pragma unroll
            for (int j = 0; j < 4; j++) b[j] = Bs[tx * 4 + j][kk];
            #pragma unroll
            for (int i = 0; i < 4; i++)
                #pragma unroll
                for (int j = 0; j < 4; j++)
                    acc[i][j] = fmaf(a[i], b[j], acc[i][j]);
        }
        __syncthreads();
    }
    #pragma unroll
    for (int i = 0; i < 4; i++) {
        size_t r = rowBase + ty * 4 + i;
        #pragma unroll
        for (int j = 0; j < 4; j++) {
            int o = colBase + tx * 4 + j;
            float s = acc[i][j] + bias[o];
            if (MODE == MM_BN) {
                s = (s - e0[o]) * rsqrtf(e1[o] + 1e-5f) * e2[o] + e3[o];
            }
            out[r * (size_t)N + o] = s;
        }
    }
}

// ---------------- MFMA bf16 GEMM: out = A(bf16) @ W(bf16)^T + bias ----------
// 128x128 tile, BK=32, 256 threads = 4 waves (2x2 of 64x64).
#define FM_BF16 0
#define FM_GELU 1
#define FM_RES 2
template <int MODE>
__global__ __launch_bounds__(256) void mfma_mm(
    const bf16* __restrict__ A,     // rows x K
    const bf16* __restrict__ W,     // N x K
    const float* __restrict__ bias, // N
    void* __restrict__ outv,        // rows x N (bf16 or f32 per MODE)
    const float* __restrict__ res,  // rows x N (MODE==FM_RES)
    int K, int N)
{
    __shared__ short Alds[128 * 32];   // 8 KB
    __shared__ short Blds[128 * 32];   // 8 KB
    int t = threadIdx.x;
    int l = t & 63;
    int w = t >> 6;
    int wm = w >> 1, wn = w & 1;
    size_t rowBase = (size_t)blockIdx.y * 128;
    int colBase = blockIdx.x * 128;
    const short* Ag = (const short*)A;
    const short* Wg = (const short*)W;

    f32x4 acc[4][4];
    #pragma unroll
    for (int i = 0; i < 4; i++)
        #pragma unroll
        for (int j = 0; j < 4; j++)
            acc[i][j] = (f32x4){0.f, 0.f, 0.f, 0.f};

    int quad = l >> 4, lm = l & 15;

    for (int k0 = 0; k0 < K; k0 += 32) {
        __syncthreads();
        #pragma unroll
        for (int it = 0; it < 2; it++) {
            int u = it * 256 + t;
            int r = u & 127, q = u >> 7;
            __builtin_amdgcn_global_load_lds(
                (const __attribute__((address_space(1))) void*)(Ag + (rowBase + r) * (size_t)K + k0 + q * 8),
                (__attribute__((address_space(3))) void*)(&Alds[u * 8]), 16, 0, 0);
            __builtin_amdgcn_global_load_lds(
                (const __attribute__((address_space(1))) void*)(Wg + ((size_t)colBase + r) * K + k0 + q * 8),
                (__attribute__((address_space(3))) void*)(&Blds[u * 8]), 16, 0, 0);
        }
        __syncthreads();

        short8 afrag[4], bfrag[4];
        #pragma unroll
        for (int mt = 0; mt < 4; mt++) {
            int row = wm * 64 + mt * 16 + lm;
            afrag[mt] = *(const short8*)&Alds[(quad * 128 + row) * 8];
        }
        #pragma unroll
        for (int nt = 0; nt < 4; nt++) {
            int col = wn * 64 + nt * 16 + lm;
            bfrag[nt] = *(const short8*)&Blds[(quad * 128 + col) * 8];
        }
        #pragma unroll
        for (int mt = 0; mt < 4; mt++)
            #pragma unroll
            for (int nt = 0; nt < 4; nt++)
                acc[mt][nt] = __builtin_amdgcn_mfma_f32_16x16x32_bf16(
                    afrag[mt], bfrag[nt], acc[mt][nt], 0, 0, 0);
    }

    #pragma unroll
    for (int mt = 0; mt < 4; mt++) {
        #pragma unroll
        for (int nt = 0; nt < 4; nt++) {
            int col = colBase + wn * 64 + nt * 16 + lm;
            float bcol = bias[col];
            f32x4 a = acc[mt][nt];
            #pragma unroll
            for (int r = 0; r < 4; r++) {
                size_t row = rowBase + wm * 64 + mt * 16 + quad * 4 + r;
                float s = a[r] + bcol;
                if (MODE == FM_GELU) {
                    s = 0.5f * s * (1.0f + erff(s * 0.70710678118654752f));
                }
                if (MODE == FM_RES) {
                    s += res[row * (size_t)N + col];
                    ((float*)outv)[row * (size_t)N + col] = s;
                } else {
                    ((bf16*)outv)[row * (size_t)N + col] = __float2bfloat16(s);
                }
            }
        }
    }
}

// ---------------- Cross attention: 1 block per (b, h), 256 threads ----------
__global__ void cross_attn_kernel(const float* __restrict__ qtok,
                                  const float* __restrict__ k,
                                  const float* __restrict__ v,
                                  float* __restrict__ qoutq) {
    int b = blockIdx.x >> 3, h = blockIdx.x & 7;
    int t = threadIdx.x;
    __shared__ float qs[8][32];
    __shared__ float sc[8][257];
    {
        int i = t >> 5, d = t & 31;
        qs[i][d] = qtok[i * 256 + h * 32 + d];
    }
    __syncthreads();
    {
        const float* kp = k + ((size_t)b * NPOOL + t) * 256 + h * 32;
        float kd[32];
        #pragma unroll
        for (int d = 0; d < 32; d++) kd[d] = kp[d];
        #pragma unroll
        for (int i = 0; i < 8; i++) {
            float s = 0.f;
            #pragma unroll
            for (int d = 0; d < 32; d++) s += qs[i][d] * kd[d];
            sc[i][t] = s * SCALE;
        }
    }
    __syncthreads();
    {
        int r = t >> 5, ln = t & 31;
        float mx = -1e30f;
        for (int j = ln; j < 256; j += 32) mx = fmaxf(mx, sc[r][j]);
        #pragma unroll
        for (int o = 16; o > 0; o >>= 1) mx = fmaxf(mx, __shfl_xor(mx, o));
        float sum = 0.f;
        for (int j = ln; j < 256; j += 32) {
            float e = __expf(sc[r][j] - mx);
            sc[r][j] = e;
            sum += e;
        }
        #pragma unroll
        for (int o = 16; o > 0; o >>= 1) sum += __shfl_xor(sum, o);
        float inv = 1.f / sum;
        for (int j = ln; j < 256; j += 32) sc[r][j] *= inv;
    }
    __syncthreads();
    {
        int i = t >> 5, d = t & 31;
        float acc = 0.f;
        for (int j = 0; j < 256; j++)
            acc += sc[i][j] * v[((size_t)b * NPOOL + j) * 256 + h * 32 + d];
        qoutq[((size_t)b * NQ + i) * 256 + h * 32 + d] = acc + qs[i][d];
    }
}

// ---------------- Window attention (MFMA): 1 block per (window, head-pair) --
// qkv bf16 (B*4096, 768), gk/gv f32 (B*8, 256), rpb (225,8).
// Writes attn probs f32 (1024,8,64,72) and P@V bf16 attno (B*4096,256).
//
// Block handles 2 heads (hpair*2, hpair*2+1) of one 8x8 window.
// A head-pair slice of a qkv row is 128B contiguous => full-cacheline fetch,
// each line consumed by exactly one block (kills the 16x over-fetch).
// 4 waves: wave w -> head (w>>1), row-half (w&1)*32.
// QK^T and P@V via mfma_f32_16x16x32_bf16 (K=32=HD fits exactly).
// LDS strides padded so 16-lane row-parallel ds_read_b128 is conflict-free.
#define QS_S 72   // qs row stride (shorts): 36 dwords, 36%32=4 -> 8 banks/16 rows
#define KS_S 72
#define VS_S 80   // 16B-aligned rows for short8 staging
#define PS_S 104  // 52 dwords, 52%32=20 -> 8 banks/16 rows
__global__ __launch_bounds__(256) void win_attn_mfma(
    const bf16* __restrict__ qkv,
    const float* __restrict__ gk,
    const float* __restrict__ gv,
    const float* __restrict__ rpb,
    float* __restrict__ attn_out,
    bf16* __restrict__ attno)
{
    int blk = blockIdx.x;
    int w = blk >> 2, hp = blk & 3;
    int b = w >> 6, wi = w & 63;
    int wy = wi >> 3, wx = wi & 7;
    int t = threadIdx.x;
    int lane = t & 63, wv = t >> 6;
    int hl = wv >> 1;            // head-local: 0/1
    int h = hp * 2 + hl;         // global head
    int msel = wv & 1;           // row-half of the 64 window tokens
    int lm = lane & 15, q4 = lane >> 4;

    // LDS: [ ps 2*64*104 shorts (overlaps qs,ks) ][ vs 72*80 shorts ]
    __shared__ __attribute__((aligned(16))) short smem[2 * 64 * PS_S + KVLEN * VS_S];
    short* ps = smem;                       // [2][64][PS_S], live after barrier 2
    short* qs = smem;                       // [64][QS_S]  (4608 shorts)
    short* ks = smem + 64 * QS_S;           // [72][KS_S]  (5184 shorts; 9792 <= 13312)
    short* vs = smem + 2 * 64 * PS_S;       // [72][VS_S]

    // ---- stage Q,K,V (head-pair slice) : 1536 x 16B chunks ----
    const short* qkvp = (const short*)qkv;
    for (int u = t; u < 1536; u += 256) {
        int seg = u >> 9;            // 0=Q 1=K 2=V (uniform per iteration)
        int r = (u >> 3) & 63;       // window-local token
        int c = u & 7;               // 16B chunk of the 64-ch slice
        int n = (wy * 8 + (r >> 3)) * GRID_ + wx * 8 + (r & 7);
        short8 val = *(const short8*)(qkvp + ((size_t)(b * NTOK + n)) * 768 + seg * 256 + hp * 64 + c * 8);
        short* dst = (seg == 0) ? &qs[r * QS_S + c * 8]
                   : (seg == 1) ? &ks[r * KS_S + c * 8]
                                : &vs[r * VS_S + c * 8];
        *(short8*)dst = val;
    }
    // ---- stage gk/gv rows 64..71 (f32 -> bf16) ----
    for (int idx = t; idx < 512; idx += 256) {
        int i = idx >> 6, d = idx & 63;
        float gkv = gk[((size_t)b * NQ + i) * 256 + hp * 64 + d];
        float gvv = gv[((size_t)b * NQ + i) * 256 + hp * 64 + d];
        ks[(64 + i) * KS_S + d] = f2bf_bits(gkv);
        vs[(64 + i) * VS_S + d] = f2bf_bits(gvv);
    }
    __syncthreads();

    // ---- S = Q @ K^T for this wave's head / row-half ----
    f32x4 acc[2][5];
    #pragma unroll
    for (int mt = 0; mt < 2; mt++)
        #pragma unroll
        for (int nt = 0; nt < 5; nt++)
            acc[mt][nt] = (f32x4){0.f, 0.f, 0.f, 0.f};

    short8 afrag[2], bfrag[5];
    #pragma unroll
    for (int mt = 0; mt < 2; mt++) {
        int row = msel * 32 + mt * 16 + lm;
        afrag[mt] = *(const short8*)&qs[row * QS_S + hl * 32 + q4 * 8];
    }
    #pragma unroll
    for (int nt = 0; nt < 5; nt++) {
        int col = nt * 16 + lm;
        int jc = (col < KVLEN) ? col : 0;     // cols 72..79 masked later
        bfrag[nt] = *(const short8*)&ks[jc * KS_S + hl * 32 + q4 * 8];
    }
    #pragma unroll
    for (int mt = 0; mt < 2; mt++)
        #pragma unroll
        for (int nt = 0; nt < 5; nt++)
            acc[mt][nt] = __builtin_amdgcn_mfma_f32_16x16x32_bf16(
                afrag[mt], bfrag[nt], acc[mt][nt], 0, 0, 0);

    // ---- wave-parallel softmax (rows per quad; reduce across 16 lanes) ----
    #pragma unroll
    for (int mt = 0; mt < 2; mt++) {
        #pragma unroll
        for (int r = 0; r < 4; r++) {
            int rowl = msel * 32 + mt * 16 + q4 * 4 + r;
            int yi = rowl >> 3, xi = rowl & 7;
            float sv[5];
            float mx = -1e30f;
            #pragma unroll
            for (int nt = 0; nt < 5; nt++) {
                float s = acc[mt][nt][r] * SCALE;
                int j = nt * 16 + lm;
                if (j < 64) {
                    int rpi = (yi - (j >> 3) + 7) * 15 + (xi - (j & 7) + 7);
                    s += rpb[rpi * 8 + h];
                } else if (j >= KVLEN) {
                    s = -1e30f;
                }
                sv[nt] = s;
                mx = fmaxf(mx, s);
            }
            #pragma unroll
            for (int o = 1; o < 16; o <<= 1) mx = fmaxf(mx, __shfl_xor(mx, o));
            float sum = 0.f;
            #pragma unroll
            for (int nt = 0; nt < 5; nt++) {
                float e = __expf(sv[nt] - mx);
                sv[nt] = e;
                sum += e;
            }
            #pragma unroll
            for (int o = 1; o < 16; o <<= 1) sum += __shfl_xor(sum, o);
            float inv = 1.f / sum;
            #pragma unroll
            for (int nt = 0; nt < 5; nt++) acc[mt][nt][r] = sv[nt] * inv;
        }
    }

    __syncthreads();   // all waves done reading qs/ks -> safe to overwrite with ps

    // ---- write attn probs (global) + P (bf16) into LDS ----
    size_t abase = ((size_t)(w * 8 + h)) * (64 * KVLEN);
    #pragma unroll
    for (int mt = 0; mt < 2; mt++) {
        #pragma unroll
        for (int r = 0; r < 4; r++) {
            int rowl = msel * 32 + mt * 16 + q4 * 4 + r;
            #pragma unroll
            for (int nt = 0; nt < 5; nt++) {
                int j = nt * 16 + lm;
                float p = acc[mt][nt][r];
                if (j < KVLEN) attn_out[abase + rowl * KVLEN + j] = p;
                ps[(hl * 64 + rowl) * PS_S + j] = f2bf_bits(p);  // cols 72..79 are exact 0
            }
        }
    }
    // zero-fill P cols 80..95 (third K-chunk padding)
    if (t < 128) {
        int hh = t >> 6, rr = t & 63;
        short8 z = {};
        *(short8*)&ps[(hh * 64 + rr) * PS_S + 80] = z;
        *(short8*)&ps[(hh * 64 + rr) * PS_S + 88] = z;
    }
    __syncthreads();

    // ---- O = P @ V ----
    f32x4 oacc[2][2];
    #pragma unroll
    for (int mt = 0; mt < 2; mt++)
        #pragma unroll
        for (int nt = 0; nt < 2; nt++)
            oacc[mt][nt] = (f32x4){0.f, 0.f, 0.f, 0.f};

    #pragma unroll
    for (int kc = 0; kc < 3; kc++) {
        short8 pa[2];
        #pragma unroll
        for (int mt = 0; mt < 2; mt++) {
            int row = msel * 32 + mt * 16 + lm;
            pa[mt] = *(const short8*)&ps[(hl * 64 + row) * PS_S + kc * 32 + q4 * 8];
        }
        #pragma unroll
        for (int nt = 0; nt < 2; nt++) {
            int d = hl * 32 + nt * 16 + lm;
            short8 bv;
            #pragma unroll
            for (int e = 0; e < 8; e++) {
                int k = kc * 32 + q4 * 8 + e;
                int kk = (k < KVLEN) ? k : 0;   // P is 0 there; keep V read in-bounds
                bv[e] = vs[kk * VS_S + d];
            }
            #pragma unroll
            for (int mt = 0; mt < 2; mt++)
                oacc[mt][nt] = __builtin_amdgcn_mfma_f32_16x16x32_bf16(
                    pa[mt], bv, oacc[mt][nt], 0, 0, 0);
        }
    }

    // ---- write attno (bf16) ----
    #pragma unroll
    for (int mt = 0; mt < 2; mt++) {
        #pragma unroll
        for (int nt = 0; nt < 2; nt++) {
            #pragma unroll
            for (int r = 0; r < 4; r++) {
                int rowl = msel * 32 + mt * 16 + q4 * 4 + r;
                int n = (wy * 8 + (rowl >> 3)) * GRID_ + wx * 8 + (rowl & 7);
                attno[((size_t)(b * NTOK + n)) * 256 + h * 32 + nt * 16 + lm] =
                    __float2bfloat16(oacc[mt][nt][r]);
            }
        }
    }
}

extern "C" void kernel_launch(void* const* d_in, const int* in_sizes, int n_in,
                              void* d_out, int out_size, void* d_ws, size_t ws_size,
                              hipStream_t stream) {
    const float* x       = (const float*)d_in[0];
    const float* qtok    = (const float*)d_in[1];
    const float* kproj_w = (const float*)d_in[2];
    const float* kproj_b = (const float*)d_in[3];
    const float* kbn_g   = (const float*)d_in[4];
    const float* kbn_b   = (const float*)d_in[5];
    const float* kbn_m   = (const float*)d_in[6];
    const float* kbn_v   = (const float*)d_in[7];
    const float* vproj_w = (const float*)d_in[8];
    const float* vproj_b = (const float*)d_in[9];
    const float* vbn_g   = (const float*)d_in[10];
    const float* vbn_b   = (const float*)d_in[11];
    const float* vbn_m   = (const float*)d_in[12];
    const float* vbn_v   = (const float*)d_in[13];
    const float* ck_w    = (const float*)d_in[14];
    const float* ck_b    = (const float*)d_in[15];
    const float* cv_w    = (const float*)d_in[16];
    const float* cv_b    = (const float*)d_in[17];
    const float* rpb     = (const float*)d_in[18];
    const float* qkv_w   = (const float*)d_in[19];
    const float* qkv_b   = (const float*)d_in[20];
    const float* proj_w  = (const float*)d_in[21];
    const float* proj_b  = (const float*)d_in[22];
    const float* n1_g    = (const float*)d_in[23];
    const float* n1_b    = (const float*)d_in[24];
    const float* n2_g    = (const float*)d_in[25];
    const float* n2_b    = (const float*)d_in[26];
    const float* fc1_w   = (const float*)d_in[27];
    const float* fc1_b   = (const float*)d_in[28];
    const float* fc2_w   = (const float*)d_in[29];
    const float* fc2_b   = (const float*)d_in[30];

    float* out_x    = (float*)d_out;                              // (16,4096,256)
    float* out_attn = (float*)d_out + (size_t)BATCH * NTOK * DIM; // (1024,8,64,72)

    const size_t ROWS = (size_t)BATCH * NTOK;                     // 65536

    // ---- workspace layout ----
    bf16* xn    = (bf16*)d_ws;                   // 16,777,216 bf16 (also xm later)
    bf16* qkvb  = xn + ROWS * 256;               // 50,331,648 bf16
    bf16* attno = qkvb + ROWS * 768;             // 16,777,216 bf16
    bf16* hbuf  = qkvb;                          // reuse qkvb+attno = 67,108,864 bf16
    bf16* wqkv  = attno + ROWS * 256;            // 196,608
    bf16* wproj = wqkv + 196608;                 // 65,536
    bf16* wfc1  = wproj + 65536;                 // 262,144
    bf16* wfc2  = wfc1 + 262144;                 // 262,144
    float* pooled = (float*)(wfc2 + 262144);     // 1,048,576 f32
    float* kbuf   = pooled + 1048576;
    float* vbuf   = kbuf + 1048576;
    float* qoutq  = vbuf + 1048576;              // 32,768 f32
    float* gkbuf  = qoutq + 32768;
    float* gvbuf  = gkbuf + 32768;
    bf16* xm = xn;

    // 0. weight conversions (independent of everything else)
    f2bf_kernel<<<dim3(768), dim3(256), 0, stream>>>(qkv_w, wqkv, 196608);
    f2bf_kernel<<<dim3(256), dim3(256), 0, stream>>>(proj_w, wproj, 65536);
    f2bf_kernel<<<dim3(1024), dim3(256), 0, stream>>>(fc1_w, wfc1, 262144);
    f2bf_kernel<<<dim3(1024), dim3(256), 0, stream>>>(fc2_w, wfc2, 262144);
    // 1. LN1 -> bf16
    ln_kernel<bf16><<<dim3(ROWS), dim3(256), 0, stream>>>(x, n1_g, n1_b, xn);
    // 2. pool
    pool_kernel<<<dim3(BATCH * NPOOL), dim3(256), 0, stream>>>(xn, pooled);
    // 3./4. k,v = proj+BN (fp32, small)
    mm_kernel<MM_BN><<<dim3(4, 64), dim3(256), 0, stream>>>(
        pooled, kproj_w, kproj_b, kbuf, 256, 256, kbn_m, kbn_v, kbn_g, kbn_b);
    mm_kernel<MM_BN><<<dim3(4, 64), dim3(256), 0, stream>>>(
        pooled, vproj_w, vproj_b, vbuf, 256, 256, vbn_m, vbn_v, vbn_g, vbn_b);
    // 5. cross attention -> qout + q
    cross_attn_kernel<<<dim3(BATCH * HEADS), dim3(256), 0, stream>>>(qtok, kbuf, vbuf, qoutq);
    // 6./7. gk, gv (fp32, tiny)
    mm_kernel<MM_PLAIN><<<dim3(4, 2), dim3(256), 0, stream>>>(
        qoutq, ck_w, ck_b, gkbuf, 256, 256, nullptr, nullptr, nullptr, nullptr);
    mm_kernel<MM_PLAIN><<<dim3(4, 2), dim3(256), 0, stream>>>(
        qoutq, cv_w, cv_b, gvbuf, 256, 256, nullptr, nullptr, nullptr, nullptr);
    // 8. qkv projection: MFMA bf16 (rows=65536, K=256, N=768)
    mfma_mm<FM_BF16><<<dim3(6, 512), dim3(256), 0, stream>>>(
        xn, wqkv, qkv_b, qkvb, nullptr, 256, 768);
    // 9. window attention (MFMA, 1 block per (window, head-pair))
    win_attn_mfma<<<dim3(1024 * 4), dim3(256), 0, stream>>>(
        qkvb, gkbuf, gvbuf, rpb, out_attn, attno);
    // 10. proj + shortcut -> out_x (MFMA, K=256, N=256)
    mfma_mm<FM_RES><<<dim3(2, 512), dim3(256), 0, stream>>>(
        attno, wproj, proj_b, out_x, x, 256, 256);
    // 11. LN2 -> bf16
    ln_kernel<bf16><<<dim3(ROWS), dim3(256), 0, stream>>>(out_x, n2_g, n2_b, xm);
    // 12. fc1 + gelu (MFMA, K=256, N=1024) -> bf16 hbuf
    mfma_mm<FM_GELU><<<dim3(8, 512), dim3(256), 0, stream>>>(
        xm, wfc1, fc1_b, hbuf, nullptr, 256, 1024);
    // 13. fc2 + residual in-place (MFMA, K=1024, N=256)
    mfma_mm<FM_RES><<<dim3(2, 512), dim3(256), 0, stream>>>(
        hbuf, wfc2, fc2_b, out_x, out_x, 1024, 256);
}

// Round 2
// 865.687 us; speedup vs baseline: 2.2214x; 1.0227x over previous
//
#include <hip/hip_runtime.h>
#include <hip/hip_bf16.h>
#include <math.h>

// Problem constants
#define BATCH 16
#define DIM 256
#define HEADS 8
#define HD 32
#define GRID_ 64
#define NTOK 4096            // GRID_*GRID_
#define WS 8
#define NQ 8
#define POOL 4
#define HP 16                // GRID_/POOL
#define NPOOL 256            // HP*HP
#define NW 8                 // GRID_/WS
#define NWTOK 64             // WS*WS
#define KVLEN 72             // NWTOK + NQ
#define SCALE 0.17677669529663687f   // HD^-0.5

typedef short short8 __attribute__((ext_vector_type(8)));
typedef float f32x4 __attribute__((ext_vector_type(4)));

typedef __hip_bfloat16 bf16;

__device__ inline short f2bf_bits(float f) {
    bf16 h = __float2bfloat16(f);
    return *reinterpret_cast<short*>(&h);
}
__device__ inline float bfbits2f(short s) {
    return __bfloat162float(*reinterpret_cast<bf16*>(&s));
}

// ---------------- float -> bf16 conversion (all 4 weight mats, 1 launch) ----
__global__ void f2bf4_kernel(const float* __restrict__ s0, bf16* __restrict__ d0,
                             const float* __restrict__ s1, bf16* __restrict__ d1,
                             const float* __restrict__ s2, bf16* __restrict__ d2,
                             const float* __restrict__ s3, bf16* __restrict__ d3) {
    int i = blockIdx.x * 256 + threadIdx.x;   // total 786432
    if (i < 196608) {
        d0[i] = __float2bfloat16(s0[i]);
    } else if (i < 262144) {
        int j = i - 196608; d1[j] = __float2bfloat16(s1[j]);
    } else if (i < 524288) {
        int j = i - 262144; d2[j] = __float2bfloat16(s2[j]);
    } else {
        int j = i - 524288; d3[j] = __float2bfloat16(s3[j]);
    }
}

// ---------------- LayerNorm: one block (256 threads) per row ----------------
__device__ inline void store_val(float* p, float v) { *p = v; }
__device__ inline void store_val(bf16* p, float v) { *p = __float2bfloat16(v); }

template <typename OT>
__global__ void ln_kernel(const float* __restrict__ x, const float* __restrict__ g,
                          const float* __restrict__ bb, OT* __restrict__ y) {
    int row = blockIdx.x;
    int t = threadIdx.x;
    float v = x[(size_t)row * 256 + t];
    float s = v, sq = v * v;
    #pragma unroll
    for (int o = 32; o > 0; o >>= 1) {
        s += __shfl_down(s, o);
        sq += __shfl_down(sq, o);
    }
    __shared__ float ls[4], lq[4];
    __shared__ float mean_s, rstd_s;
    int w = t >> 6;
    if ((t & 63) == 0) { ls[w] = s; lq[w] = sq; }
    __syncthreads();
    if (t == 0) {
        float S = ls[0] + ls[1] + ls[2] + ls[3];
        float Q = lq[0] + lq[1] + lq[2] + lq[3];
        float m = S * (1.0f / 256.0f);
        float var = Q * (1.0f / 256.0f) - m * m;
        mean_s = m;
        rstd_s = rsqrtf(var + 1e-5f);
    }
    __syncthreads();
    store_val(&y[(size_t)row * 256 + t], (v - mean_s) * rstd_s * g[t] + bb[t]);
}

// ---------------- 4x4 avg pool: xn (B,4096,256) bf16 -> pooled f32 ----------
__global__ void pool_kernel(const bf16* __restrict__ xn, float* __restrict__ pooled) {
    int bp = blockIdx.x;          // b*256 + p
    int b = bp >> 8, p = bp & 255;
    int ph = p >> 4, pw = p & 15;
    int c = threadIdx.x;
    float s = 0.f;
    #pragma unroll
    for (int i = 0; i < 4; i++)
        #pragma unroll
        for (int j = 0; j < 4; j++) {
            int n = (ph * 4 + i) * GRID_ + pw * 4 + j;
            s += __bfloat162float(xn[((size_t)b * NTOK + n) * 256 + c]);
        }
    pooled[(size_t)bp * 256 + c] = s * 0.0625f;
}

// ---------------- small fp32 tiled GEMM (kproj/vproj/gk/gv) -----------------
#define MM_PLAIN 0
#define MM_BN 1      // e0=mean e1=var e2=gamma e3=beta
template <int MODE>
__global__ void mm_kernel(const float* __restrict__ A, const float* __restrict__ W,
                          const float* __restrict__ bias, float* __restrict__ out,
                          int K, int N,
                          const float* __restrict__ e0, const float* __restrict__ e1,
                          const float* __restrict__ e2, const float* __restrict__ e3) {
    __shared__ float As[64][17];
    __shared__ float Bs[64][17];
    int t = threadIdx.x;
    int ty = t >> 4, tx = t & 15;
    size_t rowBase = (size_t)blockIdx.y * 64;
    int colBase = blockIdx.x * 64;
    float acc[4][4] = {};
    for (int k0 = 0; k0 < K; k0 += 16) {
        #pragma unroll
        for (int l = 0; l < 4; l++) {
            int e = t + l * 256;
            int r = e >> 4, kk = e & 15;
            As[r][kk] = A[(rowBase + r) * (size_t)K + k0 + kk];
            Bs[r][kk] = W[((size_t)colBase + r) * K + k0 + kk];
        }
        __syncthreads();
        #pragma unroll
        for (int kk = 0; kk < 16; kk++) {
            float a[4], b[4];
            #pragma unroll
            for (int i = 0; i < 4; i++) a[i] = As[ty * 4 + i][kk];
            #pragma unroll
            for (int j = 0; j < 4; j++) b[j] = Bs[tx * 4 + j][kk];
            #pragma unroll
            for (int i = 0; i < 4; i++)
                #pragma unroll
                for (int j = 0; j < 4; j++)
                    acc[i][j] = fmaf(a[i], b[j], acc[i][j]);
        }
        __syncthreads();
    }
    #pragma unroll
    for (int i = 0; i < 4; i++) {
        size_t r = rowBase + ty * 4 + i;
        #pragma unroll
        for (int j = 0; j < 4; j++) {
            int o = colBase + tx * 4 + j;
            float s = acc[i][j] + bias[o];
            if (MODE == MM_BN) {
                s = (s - e0[o]) * rsqrtf(e1[o] + 1e-5f) * e2[o] + e3[o];
            }
            out[r * (size_t)N + o] = s;
        }
    }
}

// ---------------- MFMA bf16 GEMM: out = A(bf16) @ W(bf16)^T + bias ----------
// 128x128 tile, BK=32, 256 threads = 4 waves (2x2 of 64x64).
// T3-min pipeline: double-buffered LDS; issue next-tile global_load_lds BEFORE
// current tile's ds_read+MFMA; single __syncthreads per K-step (its implicit
// vmcnt(0)+lgkmcnt(0) drain is exactly the wanted wait). Race-free: ds_reads
// of buf are retired (lgkmcnt in-wave) before the barrier each wave passes
// before any wave can issue stage() into that buf on the next iteration.
#define FM_BF16 0
#define FM_GELU 1
#define FM_RES 2
template <int MODE>
__global__ __launch_bounds__(256) void mfma_mm(
    const bf16* __restrict__ A,     // rows x K
    const bf16* __restrict__ W,     // N x K
    const float* __restrict__ bias, // N
    void* __restrict__ outv,        // rows x N (bf16 or f32 per MODE)
    const float* __restrict__ res,  // rows x N (MODE==FM_RES)
    int K, int N)
{
    __shared__ short Alds[2][128 * 32];   // 16 KB
    __shared__ short Blds[2][128 * 32];   // 16 KB
    int t = threadIdx.x;
    int l = t & 63;
    int w = t >> 6;
    int wm = w >> 1, wn = w & 1;
    size_t rowBase = (size_t)blockIdx.y * 128;
    int colBase = blockIdx.x * 128;
    const short* Ag = (const short*)A;
    const short* Wg = (const short*)W;

    f32x4 acc[4][4];
    #pragma unroll
    for (int i = 0; i < 4; i++)
        #pragma unroll
        for (int j = 0; j < 4; j++)
            acc[i][j] = (f32x4){0.f, 0.f, 0.f, 0.f};

    int quad = l >> 4, lm = l & 15;

    auto stage = [&](int buf, int k0) {
        #pragma unroll
        for (int it = 0; it < 2; it++) {
            int u = it * 256 + t;
            int r = u & 127, q = u >> 7;
            __builtin_amdgcn_global_load_lds(
                (const __attribute__((address_space(1))) void*)(Ag + (rowBase + r) * (size_t)K + k0 + q * 8),
                (__attribute__((address_space(3))) void*)(&Alds[buf][u * 8]), 16, 0, 0);
            __builtin_amdgcn_global_load_lds(
                (const __attribute__((address_space(1))) void*)(Wg + ((size_t)colBase + r) * K + k0 + q * 8),
                (__attribute__((address_space(3))) void*)(&Blds[buf][u * 8]), 16, 0, 0);
        }
    };

    stage(0, 0);
    __syncthreads();                 // drains vmcnt(0): buf0 ready
    int nk = K >> 5;
    for (int kt = 0; kt < nk; kt++) {
        int buf = kt & 1;
        if (kt + 1 < nk) stage(buf ^ 1, (kt + 1) << 5);   // overlaps with MFMA below

        short8 afrag[4], bfrag[4];
        #pragma unroll
        for (int mt = 0; mt < 4; mt++) {
            int row = wm * 64 + mt * 16 + lm;
            afrag[mt] = *(const short8*)&Alds[buf][(quad * 128 + row) * 8];
        }
        #pragma unroll
        for (int nt = 0; nt < 4; nt++) {
            int col = wn * 64 + nt * 16 + lm;
            bfrag[nt] = *(const short8*)&Blds[buf][(quad * 128 + col) * 8];
        }
        #pragma unroll
        for (int mt = 0; mt < 4; mt++)
            #pragma unroll
            for (int nt = 0; nt < 4; nt++)
                acc[mt][nt] = __builtin_amdgcn_mfma_f32_16x16x32_bf16(
                    afrag[mt], bfrag[nt], acc[mt][nt], 0, 0, 0);
        __syncthreads();             // drains vmcnt(0)+lgkmcnt(0): next buf ready
    }

    #pragma unroll
    for (int mt = 0; mt < 4; mt++) {
        #pragma unroll
        for (int nt = 0; nt < 4; nt++) {
            int col = colBase + wn * 64 + nt * 16 + lm;
            float bcol = bias[col];
            f32x4 a = acc[mt][nt];
            #pragma unroll
            for (int r = 0; r < 4; r++) {
                size_t row = rowBase + wm * 64 + mt * 16 + quad * 4 + r;
                float s = a[r] + bcol;
                if (MODE == FM_GELU) {
                    s = 0.5f * s * (1.0f + erff(s * 0.70710678118654752f));
                }
                if (MODE == FM_RES) {
                    s += res[row * (size_t)N + col];
                    ((float*)outv)[row * (size_t)N + col] = s;
                } else {
                    ((bf16*)outv)[row * (size_t)N + col] = __float2bfloat16(s);
                }
            }
        }
    }
}

// ---------------- proj + residual + LayerNorm2 fused ------------------------
// out_x = attno @ proj_w^T + proj_b + x   (f32, pre-LN, final-residual base)
// xm    = LN(out_x; n2_g, n2_b)           (bf16, fc1 input)
// BM=128, BN=256 (full width) so each wave owns whole rows -> LN stats are
// register adds over nt + 4x shfl_xor over the 16-lane quad group.
__global__ __launch_bounds__(256) void proj_res_ln(
    const bf16* __restrict__ A,      // 65536 x 256
    const bf16* __restrict__ W,      // 256 x 256
    const float* __restrict__ bias,
    const float* __restrict__ res,   // x
    const float* __restrict__ g,     // n2_g
    const float* __restrict__ bb,    // n2_b
    float* __restrict__ outx,
    bf16* __restrict__ xm)
{
    __shared__ short Alds[2][128 * 32];   // 16 KB
    __shared__ short Blds[2][256 * 32];   // 32 KB
    int t = threadIdx.x;
    int lane = t & 63, w = t >> 6;
    int quad = lane >> 4, lm = lane & 15;
    size_t rowBase = (size_t)blockIdx.x * 128;
    const short* Ag = (const short*)A;
    const short* Wg = (const short*)W;

    f32x4 acc[2][16];
    #pragma unroll
    for (int mt = 0; mt < 2; mt++)
        #pragma unroll
        for (int nt = 0; nt < 16; nt++)
            acc[mt][nt] = (f32x4){0.f, 0.f, 0.f, 0.f};

    auto stage = [&](int buf, int k0) {
        #pragma unroll
        for (int it = 0; it < 2; it++) {
            int u = it * 256 + t;
            int r = u & 127, q = u >> 7;
            __builtin_amdgcn_global_load_lds(
                (const __attribute__((address_space(1))) void*)(Ag + (rowBase + r) * 256 + k0 + q * 8),
                (__attribute__((address_space(3))) void*)(&Alds[buf][u * 8]), 16, 0, 0);
        }
        #pragma unroll
        for (int it = 0; it < 4; it++) {
            int u = it * 256 + t;
            int r = u & 255, q = u >> 8;
            __builtin_amdgcn_global_load_lds(
                (const __attribute__((address_space(1))) void*)(Wg + (size_t)r * 256 + k0 + q * 8),
                (__attribute__((address_space(3))) void*)(&Blds[buf][u * 8]), 16, 0, 0);
        }
    };

    stage(0, 0);
    __syncthreads();
    #pragma unroll 1
    for (int kt = 0; kt < 8; kt++) {
        int buf = kt & 1;
        if (kt < 7) stage(buf ^ 1, (kt + 1) * 32);
        short8 af[2];
        #pragma unroll
        for (int mt = 0; mt < 2; mt++) {
            int row = w * 32 + mt * 16 + lm;
            af[mt] = *(const short8*)&Alds[buf][(quad * 128 + row) * 8];
        }
        #pragma unroll
        for (int nt = 0; nt < 16; nt++) {
            int col = nt * 16 + lm;
            short8 bfv = *(const short8*)&Blds[buf][(quad * 256 + col) * 8];
            #pragma unroll
            for (int mt = 0; mt < 2; mt++)
                acc[mt][nt] = __builtin_amdgcn_mfma_f32_16x16x32_bf16(
                    af[mt], bfv, acc[mt][nt], 0, 0, 0);
        }
        __syncthreads();
    }

    float biasr[16], gr[16], br2[16];
    #pragma unroll
    for (int nt = 0; nt < 16; nt++) {
        int col = nt * 16 + lm;
        biasr[nt] = bias[col];
        gr[nt] = g[col];
        br2[nt] = bb[col];
    }
    #pragma unroll
    for (int mt = 0; mt < 2; mt++) {
        #pragma unroll
        for (int r = 0; r < 4; r++) {
            size_t row = rowBase + w * 32 + mt * 16 + quad * 4 + r;
            float sum = 0.f, sq = 0.f;
            #pragma unroll
            for (int nt = 0; nt < 16; nt++) {
                int col = nt * 16 + lm;
                float s = acc[mt][nt][r] + biasr[nt] + res[row * 256 + col];
                acc[mt][nt][r] = s;
                sum += s;
                sq += s * s;
            }
            #pragma unroll
            for (int o = 1; o < 16; o <<= 1) {
                sum += __shfl_xor(sum, o);
                sq += __shfl_xor(sq, o);
            }
            float m = sum * (1.0f / 256.0f);
            float var = sq * (1.0f / 256.0f) - m * m;
            float rstd = rsqrtf(var + 1e-5f);
            #pragma unroll
            for (int nt = 0; nt < 16; nt++) {
                int col = nt * 16 + lm;
                float s = acc[mt][nt][r];
                outx[row * 256 + col] = s;
                xm[row * 256 + col] = __float2bfloat16((s - m) * rstd * gr[nt] + br2[nt]);
            }
        }
    }
}

// ---------------- Cross attention: 1 block per (b, h), 256 threads ----------
__global__ void cross_attn_kernel(const float* __restrict__ qtok,
                                  const float* __restrict__ k,
                                  const float* __restrict__ v,
                                  float* __restrict__ qoutq) {
    int b = blockIdx.x >> 3, h = blockIdx.x & 7;
    int t = threadIdx.x;
    __shared__ float qs[8][32];
    __shared__ float sc[8][257];
    {
        int i = t >> 5, d = t & 31;
        qs[i][d] = qtok[i * 256 + h * 32 + d];
    }
    __syncthreads();
    {
        const float* kp = k + ((size_t)b * NPOOL + t) * 256 + h * 32;
        float kd[32];
        #pragma unroll
        for (int d = 0; d < 32; d++) kd[d] = kp[d];
        #pragma unroll
        for (int i = 0; i < 8; i++) {
            float s = 0.f;
            #pragma unroll
            for (int d = 0; d < 32; d++) s += qs[i][d] * kd[d];
            sc[i][t] = s * SCALE;
        }
    }
    __syncthreads();
    {
        int r = t >> 5, ln = t & 31;
        float mx = -1e30f;
        for (int j = ln; j < 256; j += 32) mx = fmaxf(mx, sc[r][j]);
        #pragma unroll
        for (int o = 16; o > 0; o >>= 1) mx = fmaxf(mx, __shfl_xor(mx, o));
        float sum = 0.f;
        for (int j = ln; j < 256; j += 32) {
            float e = __expf(sc[r][j] - mx);
            sc[r][j] = e;
            sum += e;
        }
        #pragma unroll
        for (int o = 16; o > 0; o >>= 1) sum += __shfl_xor(sum, o);
        float inv = 1.f / sum;
        for (int j = ln; j < 256; j += 32) sc[r][j] *= inv;
    }
    __syncthreads();
    {
        int i = t >> 5, d = t & 31;
        float acc = 0.f;
        #pragma unroll 4
        for (int j = 0; j < 256; j++)
            acc += sc[i][j] * v[((size_t)b * NPOOL + j) * 256 + h * 32 + d];
        qoutq[((size_t)b * NQ + i) * 256 + h * 32 + d] = acc + qs[i][d];
    }
}

// ---------------- Window attention (MFMA): 1 block per (window, head-pair) --
#define QS_S 72   // qs row stride (shorts)
#define KS_S 72
#define VS_S 80   // 16B-aligned rows for short8 staging
#define PS_S 104
__global__ __launch_bounds__(256) void win_attn_mfma(
    const bf16* __restrict__ qkv,
    const float* __restrict__ gk,
    const float* __restrict__ gv,
    const float* __restrict__ rpb,
    float* __restrict__ attn_out,
    bf16* __restrict__ attno)
{
    int blk = blockIdx.x;
    int w = blk >> 2, hp = blk & 3;
    int b = w >> 6, wi = w & 63;
    int wy = wi >> 3, wx = wi & 7;
    int t = threadIdx.x;
    int lane = t & 63, wv = t >> 6;
    int hl = wv >> 1;            // head-local: 0/1
    int h = hp * 2 + hl;         // global head
    int msel = wv & 1;           // row-half of the 64 window tokens
    int lm = lane & 15, q4 = lane >> 4;

    // LDS: [ ps 2*64*104 shorts (overlaps qs,ks,rpbs) ][ vs 72*80 shorts ]
    __shared__ __attribute__((aligned(16))) short smem[2 * 64 * PS_S + KVLEN * VS_S];
    short* ps = smem;                       // [2][64][PS_S], live after barrier 2
    short* qs = smem;                       // [64][QS_S]  (4608 shorts)
    short* ks = smem + 64 * QS_S;           // [72][KS_S]  ([4608..9792))
    short* rpbs = smem + 9792;              // 1800 shorts ([9792..11592) < 13312)
    short* vs = smem + 2 * 64 * PS_S;       // [72][VS_S]

    // ---- stage Q,K,V (head-pair slice) : 1536 x 16B chunks ----
    const short* qkvp = (const short*)qkv;
    for (int u = t; u < 1536; u += 256) {
        int seg = u >> 9;            // 0=Q 1=K 2=V (uniform per iteration)
        int r = (u >> 3) & 63;       // window-local token
        int c = u & 7;               // 16B chunk of the 64-ch slice
        int n = (wy * 8 + (r >> 3)) * GRID_ + wx * 8 + (r & 7);
        short8 val = *(const short8*)(qkvp + ((size_t)(b * NTOK + n)) * 768 + seg * 256 + hp * 64 + c * 8);
        short* dst = (seg == 0) ? &qs[r * QS_S + c * 8]
                   : (seg == 1) ? &ks[r * KS_S + c * 8]
                                : &vs[r * VS_S + c * 8];
        *(short8*)dst = val;
    }
    // ---- stage rpb table (bf16) into the dead LDS gap ----
    for (int i = t; i < 1800; i += 256) rpbs[i] = f2bf_bits(rpb[i]);
    // ---- stage gk/gv rows 64..71 (f32 -> bf16) ----
    for (int idx = t; idx < 512; idx += 256) {
        int i = idx >> 6, d = idx & 63;
        float gkv = gk[((size_t)b * NQ + i) * 256 + hp * 64 + d];
        float gvv = gv[((size_t)b * NQ + i) * 256 + hp * 64 + d];
        ks[(64 + i) * KS_S + d] = f2bf_bits(gkv);
        vs[(64 + i) * VS_S + d] = f2bf_bits(gvv);
    }
    __syncthreads();

    // ---- S = Q @ K^T for this wave's head / row-half ----
    f32x4 acc[2][5];
    #pragma unroll
    for (int mt = 0; mt < 2; mt++)
        #pragma unroll
        for (int nt = 0; nt < 5; nt++)
            acc[mt][nt] = (f32x4){0.f, 0.f, 0.f, 0.f};

    short8 afrag[2], bfrag[5];
    #pragma unroll
    for (int mt = 0; mt < 2; mt++) {
        int row = msel * 32 + mt * 16 + lm;
        afrag[mt] = *(const short8*)&qs[row * QS_S + hl * 32 + q4 * 8];
    }
    #pragma unroll
    for (int nt = 0; nt < 5; nt++) {
        int col = nt * 16 + lm;
        int jc = (col < KVLEN) ? col : 0;     // cols 72..79 masked later
        bfrag[nt] = *(const short8*)&ks[jc * KS_S + hl * 32 + q4 * 8];
    }
    #pragma unroll
    for (int mt = 0; mt < 2; mt++)
        #pragma unroll
        for (int nt = 0; nt < 5; nt++)
            acc[mt][nt] = __builtin_amdgcn_mfma_f32_16x16x32_bf16(
                afrag[mt], bfrag[nt], acc[mt][nt], 0, 0, 0);

    // ---- wave-parallel softmax (rows per quad; reduce across 16 lanes) ----
    #pragma unroll
    for (int mt = 0; mt < 2; mt++) {
        #pragma unroll
        for (int r = 0; r < 4; r++) {
            int rowl = msel * 32 + mt * 16 + q4 * 4 + r;
            int yi = rowl >> 3, xi = rowl & 7;
            float sv[5];
            float mx = -1e30f;
            #pragma unroll
            for (int nt = 0; nt < 5; nt++) {
                float s = acc[mt][nt][r] * SCALE;
                int j = nt * 16 + lm;
                if (j < 64) {
                    int rpi = (yi - (j >> 3) + 7) * 15 + (xi - (j & 7) + 7);
                    s += bfbits2f(rpbs[rpi * 8 + h]);
                } else if (j >= KVLEN) {
                    s = -1e30f;
                }
                sv[nt] = s;
                mx = fmaxf(mx, s);
            }
            #pragma unroll
            for (int o = 1; o < 16; o <<= 1) mx = fmaxf(mx, __shfl_xor(mx, o));
            float sum = 0.f;
            #pragma unroll
            for (int nt = 0; nt < 5; nt++) {
                float e = __expf(sv[nt] - mx);
                sv[nt] = e;
                sum += e;
            }
            #pragma unroll
            for (int o = 1; o < 16; o <<= 1) sum += __shfl_xor(sum, o);
            float inv = 1.f / sum;
            #pragma unroll
            for (int nt = 0; nt < 5; nt++) acc[mt][nt][r] = sv[nt] * inv;
        }
    }

    __syncthreads();   // all waves done reading qs/ks/rpbs -> overwrite with ps

    // ---- write attn probs (global) + P (bf16) into LDS ----
    size_t abase = ((size_t)(w * 8 + h)) * (64 * KVLEN);
    #pragma unroll
    for (int mt = 0; mt < 2; mt++) {
        #pragma unroll
        for (int r = 0; r < 4; r++) {
            int rowl = msel * 32 + mt * 16 + q4 * 4 + r;
            #pragma unroll
            for (int nt = 0; nt < 5; nt++) {
                int j = nt * 16 + lm;
                float p = acc[mt][nt][r];
                if (j < KVLEN) attn_out[abase + rowl * KVLEN + j] = p;
                ps[(hl * 64 + rowl) * PS_S + j] = f2bf_bits(p);  // cols 72..79 exact 0
            }
        }
    }
    // zero-fill P cols 80..95 (third K-chunk padding)
    if (t < 128) {
        int hh = t >> 6, rr = t & 63;
        short8 z = {};
        *(short8*)&ps[(hh * 64 + rr) * PS_S + 80] = z;
        *(short8*)&ps[(hh * 64 + rr) * PS_S + 88] = z;
    }
    __syncthreads();

    // ---- O = P @ V ----
    f32x4 oacc[2][2];
    #pragma unroll
    for (int mt = 0; mt < 2; mt++)
        #pragma unroll
        for (int nt = 0; nt < 2; nt++)
            oacc[mt][nt] = (f32x4){0.f, 0.f, 0.f, 0.f};

    #pragma unroll
    for (int kc = 0; kc < 3; kc++) {
        short8 pa[2];
        #pragma unroll
        for (int mt = 0; mt < 2; mt++) {
            int row = msel * 32 + mt * 16 + lm;
            pa[mt] = *(const short8*)&ps[(hl * 64 + row) * PS_S + kc * 32 + q4 * 8];
        }
        #pragma unroll
        for (int nt = 0; nt < 2; nt++) {
            int d = hl * 32 + nt * 16 + lm;
            short8 bv;
            #pragma unroll
            for (int e = 0; e < 8; e++) {
                int k = kc * 32 + q4 * 8 + e;
                int kk = (k < KVLEN) ? k : 0;   // P is 0 there; keep V read in-bounds
                bv[e] = vs[kk * VS_S + d];
            }
            #pragma unroll
            for (int mt = 0; mt < 2; mt++)
                oacc[mt][nt] = __builtin_amdgcn_mfma_f32_16x16x32_bf16(
                    pa[mt], bv, oacc[mt][nt], 0, 0, 0);
        }
    }

    // ---- write attno (bf16) ----
    #pragma unroll
    for (int mt = 0; mt < 2; mt++) {
        #pragma unroll
        for (int nt = 0; nt < 2; nt++) {
            #pragma unroll
            for (int r = 0; r < 4; r++) {
                int rowl = msel * 32 + mt * 16 + q4 * 4 + r;
                int n = (wy * 8 + (rowl >> 3)) * GRID_ + wx * 8 + (rowl & 7);
                attno[((size_t)(b * NTOK + n)) * 256 + h * 32 + nt * 16 + lm] =
                    __float2bfloat16(oacc[mt][nt][r]);
            }
        }
    }
}

extern "C" void kernel_launch(void* const* d_in, const int* in_sizes, int n_in,
                              void* d_out, int out_size, void* d_ws, size_t ws_size,
                              hipStream_t stream) {
    const float* x       = (const float*)d_in[0];
    const float* qtok    = (const float*)d_in[1];
    const float* kproj_w = (const float*)d_in[2];
    const float* kproj_b = (const float*)d_in[3];
    const float* kbn_g   = (const float*)d_in[4];
    const float* kbn_b   = (const float*)d_in[5];
    const float* kbn_m   = (const float*)d_in[6];
    const float* kbn_v   = (const float*)d_in[7];
    const float* vproj_w = (const float*)d_in[8];
    const float* vproj_b = (const float*)d_in[9];
    const float* vbn_g   = (const float*)d_in[10];
    const float* vbn_b   = (const float*)d_in[11];
    const float* vbn_m   = (const float*)d_in[12];
    const float* vbn_v   = (const float*)d_in[13];
    const float* ck_w    = (const float*)d_in[14];
    const float* ck_b    = (const float*)d_in[15];
    const float* cv_w    = (const float*)d_in[16];
    const float* cv_b    = (const float*)d_in[17];
    const float* rpb     = (const float*)d_in[18];
    const float* qkv_w   = (const float*)d_in[19];
    const float* qkv_b   = (const float*)d_in[20];
    const float* proj_w  = (const float*)d_in[21];
    const float* proj_b  = (const float*)d_in[22];
    const float* n1_g    = (const float*)d_in[23];
    const float* n1_b    = (const float*)d_in[24];
    const float* n2_g    = (const float*)d_in[25];
    const float* n2_b    = (const float*)d_in[26];
    const float* fc1_w   = (const float*)d_in[27];
    const float* fc1_b   = (const float*)d_in[28];
    const float* fc2_w   = (const float*)d_in[29];
    const float* fc2_b   = (const float*)d_in[30];

    float* out_x    = (float*)d_out;                              // (16,4096,256)
    float* out_attn = (float*)d_out + (size_t)BATCH * NTOK * DIM; // (1024,8,64,72)

    const size_t ROWS = (size_t)BATCH * NTOK;                     // 65536

    // ---- workspace layout ----
    bf16* xn    = (bf16*)d_ws;                   // 16,777,216 bf16 (also xm later)
    bf16* qkvb  = xn + ROWS * 256;               // 50,331,648 bf16
    bf16* attno = qkvb + ROWS * 768;             // 16,777,216 bf16
    bf16* hbuf  = qkvb;                          // reuse qkvb+attno = 67,108,864 bf16
    bf16* wqkv  = attno + ROWS * 256;            // 196,608
    bf16* wproj = wqkv + 196608;                 // 65,536
    bf16* wfc1  = wproj + 65536;                 // 262,144
    bf16* wfc2  = wfc1 + 262144;                 // 262,144
    float* pooled = (float*)(wfc2 + 262144);     // 1,048,576 f32
    float* kbuf   = pooled + 1048576;
    float* vbuf   = kbuf + 1048576;
    float* qoutq  = vbuf + 1048576;              // 32,768 f32
    float* gkbuf  = qoutq + 32768;
    float* gvbuf  = gkbuf + 32768;
    bf16* xm = xn;

    // 0. weight conversions (1 launch)
    f2bf4_kernel<<<dim3(3072), dim3(256), 0, stream>>>(
        qkv_w, wqkv, proj_w, wproj, fc1_w, wfc1, fc2_w, wfc2);
    // 1. LN1 -> bf16
    ln_kernel<bf16><<<dim3(ROWS), dim3(256), 0, stream>>>(x, n1_g, n1_b, xn);
    // 2. pool
    pool_kernel<<<dim3(BATCH * NPOOL), dim3(256), 0, stream>>>(xn, pooled);
    // 3./4. k,v = proj+BN (fp32, small)
    mm_kernel<MM_BN><<<dim3(4, 64), dim3(256), 0, stream>>>(
        pooled, kproj_w, kproj_b, kbuf, 256, 256, kbn_m, kbn_v, kbn_g, kbn_b);
    mm_kernel<MM_BN><<<dim3(4, 64), dim3(256), 0, stream>>>(
        pooled, vproj_w, vproj_b, vbuf, 256, 256, vbn_m, vbn_v, vbn_g, vbn_b);
    // 5. cross attention -> qout + q
    cross_attn_kernel<<<dim3(BATCH * HEADS), dim3(256), 0, stream>>>(qtok, kbuf, vbuf, qoutq);
    // 6./7. gk, gv (fp32, tiny)
    mm_kernel<MM_PLAIN><<<dim3(4, 2), dim3(256), 0, stream>>>(
        qoutq, ck_w, ck_b, gkbuf, 256, 256, nullptr, nullptr, nullptr, nullptr);
    mm_kernel<MM_PLAIN><<<dim3(4, 2), dim3(256), 0, stream>>>(
        qoutq, cv_w, cv_b, gvbuf, 256, 256, nullptr, nullptr, nullptr, nullptr);
    // 8. qkv projection: MFMA bf16 (rows=65536, K=256, N=768)
    mfma_mm<FM_BF16><<<dim3(6, 512), dim3(256), 0, stream>>>(
        xn, wqkv, qkv_b, qkvb, nullptr, 256, 768);
    // 9. window attention (MFMA, 1 block per (window, head-pair))
    win_attn_mfma<<<dim3(1024 * 4), dim3(256), 0, stream>>>(
        qkvb, gkbuf, gvbuf, rpb, out_attn, attno);
    // 10.+11. proj + shortcut + LN2 fused -> out_x (f32), xm (bf16)
    proj_res_ln<<<dim3(512), dim3(256), 0, stream>>>(
        attno, wproj, proj_b, x, n2_g, n2_b, out_x, xm);
    // 12. fc1 + gelu (MFMA, K=256, N=1024) -> bf16 hbuf
    mfma_mm<FM_GELU><<<dim3(8, 512), dim3(256), 0, stream>>>(
        xm, wfc1, fc1_b, hbuf, nullptr, 256, 1024);
    // 13. fc2 + residual in-place (MFMA, K=1024, N=256)
    mfma_mm<FM_RES><<<dim3(2, 512), dim3(256), 0, stream>>>(
        hbuf, wfc2, fc2_b, out_x, out_x, 1024, 256);
}